// Round 17
// baseline (3840.976 us; speedup 1.0000x reference)
//
#include <hip/hip_runtime.h>

#define BATCH 64
#define LEN   2048
#define NIN   128
#define NH    256

typedef float f32x4 __attribute__((ext_vector_type(4)));
typedef float f32x2 __attribute__((ext_vector_type(2)));

// ---------------------------------------------------------------------------
// FROZEN ARITHMETIC (R7: absmax == 0.0). Do not touch:
//  - dots: single-accumulator, k-ascending fmaf chains from 0
//  - pre = (xw + acc) + bias, left-assoc, no contraction
//  - tanh = EmitFastTanh(with_fma=true): clamp ±7.99881172180175781,
//    fmaf Horner, IEEE f32 divide, |x|<0.0004 passthrough
// ---------------------------------------------------------------------------
__device__ __forceinline__ float tanh_xla_fma_f32(float x) {
  const float kClamp = 7.99881172180175781f;
  float xc = fmaxf(x, -kClamp);
  xc = fminf(xc, kClamp);
  float x2 = xc * xc;
  float num = fmaf(x2, -2.76076847742355e-16f, 2.00018790482477e-13f);
  num = fmaf(x2, num, -8.60467152213735e-11f);
  num = fmaf(x2, num, 5.12229709037114e-08f);
  num = fmaf(x2, num, 1.48572235717979e-05f);
  num = fmaf(x2, num, 6.37261928875436e-04f);
  num = fmaf(x2, num, 4.89352455891786e-03f);
  num = xc * num;
  float den = fmaf(x2, 1.19825839466702e-06f, 1.18534705686654e-04f);
  den = fmaf(x2, den, 2.26843463243900e-03f);
  den = fmaf(x2, den, 4.89352518554385e-03f);
  float r = num / den;
  return (fabsf(x) < 0.0004f) ? x : r;
}

// R8-R16 lesson: any weight set the RA *could* shuffle between files gets
// demoted with per-use copies in the loop. Fix: AGPR file EXACTLY full
// (rnn: 64 quads = 256 AGPRs; xw: 32 quads = 128), arch VGPRs = working set
// only, and ALL supply+compute emitted as pre-interleaved asm triplets
// [read(next), readlane(next), fma(cur)] so every fma is >=6cyc from its
// operands' writes and chain fmas are exactly 6cyc apart (4cyc dep: 0 stall).

#define REP64(M) M(0) M(1) M(2) M(3) M(4) M(5) M(6) M(7) \
  M(8) M(9) M(10) M(11) M(12) M(13) M(14) M(15) \
  M(16) M(17) M(18) M(19) M(20) M(21) M(22) M(23) \
  M(24) M(25) M(26) M(27) M(28) M(29) M(30) M(31) \
  M(32) M(33) M(34) M(35) M(36) M(37) M(38) M(39) \
  M(40) M(41) M(42) M(43) M(44) M(45) M(46) M(47) \
  M(48) M(49) M(50) M(51) M(52) M(53) M(54) M(55) \
  M(56) M(57) M(58) M(59) M(60) M(61) M(62) M(63)
#define REP32(M) M(0) M(1) M(2) M(3) M(4) M(5) M(6) M(7) \
  M(8) M(9) M(10) M(11) M(12) M(13) M(14) M(15) \
  M(16) M(17) M(18) M(19) M(20) M(21) M(22) M(23) \
  M(24) M(25) M(26) M(27) M(28) M(29) M(30) M(31)

#define AQ_DECL(n) float aq##n##x, aq##n##y, aq##n##z, aq##n##w;
#define AQ_LOAD(n) { f32x4 v = wrow[n]; \
  asm("v_accvgpr_write_b32 %0, %1" : "=a"(aq##n##x) : "v"(v.x)); \
  asm("v_accvgpr_write_b32 %0, %1" : "=a"(aq##n##y) : "v"(v.y)); \
  asm("v_accvgpr_write_b32 %0, %1" : "=a"(aq##n##z) : "v"(v.z)); \
  asm("v_accvgpr_write_b32 %0, %1" : "=a"(aq##n##w) : "v"(v.w)); }

#define BANKS float w0A,w1A,w2A,w3A,w0B,w1B,w2B,w3B; \
              float s0A,s1A,s2A,s3A,s0B,s1B,s2B,s3B;

// ---- rnn blocks: h[4n+c] = lane n, comp c of hq ---------------------------
// prologue: fill bank A with quad 0 (lane 0)
#define QLD(B) asm volatile( \
  "v_accvgpr_read_b32 %[w0], %[ax]\n\t" \
  "v_readlane_b32 %[s0], %[hx], 0\n\t" \
  "v_accvgpr_read_b32 %[w1], %[ay]\n\t" \
  "v_readlane_b32 %[s1], %[hy], 0\n\t" \
  "v_accvgpr_read_b32 %[w2], %[az]\n\t" \
  "v_readlane_b32 %[s2], %[hz], 0\n\t" \
  "v_accvgpr_read_b32 %[w3], %[aw]\n\t" \
  "v_readlane_b32 %[s3], %[hw], 0" \
  : [w0]"=&v"(w0##B), [w1]"=&v"(w1##B), [w2]"=&v"(w2##B), [w3]"=&v"(w3##B), \
    [s0]"=&s"(s0##B), [s1]"=&s"(s1##B), [s2]"=&s"(s2##B), [s3]"=&s"(s3##B) \
  : [ax]"a"(aq0x), [ay]"a"(aq0y), [az]"a"(aq0z), [aw]"a"(aq0w), \
    [hx]"v"(hq.x), [hy]"v"(hq.y), [hz]"v"(hq.z), [hw]"v"(hq.w));

// consume bank CB (quad n), load bank NB (quad np = n+1, lane np)
#define QS(n, np, CB, NB) asm volatile( \
  "v_accvgpr_read_b32 %[nw0], %[ax]\n\t" \
  "v_readlane_b32 %[ns0], %[hx], %[ln]\n\t" \
  "v_fma_f32 %[a], %[cs0], %[cw0], %[a]\n\t" \
  "v_accvgpr_read_b32 %[nw1], %[ay]\n\t" \
  "v_readlane_b32 %[ns1], %[hy], %[ln]\n\t" \
  "v_fma_f32 %[a], %[cs1], %[cw1], %[a]\n\t" \
  "v_accvgpr_read_b32 %[nw2], %[az]\n\t" \
  "v_readlane_b32 %[ns2], %[hz], %[ln]\n\t" \
  "v_fma_f32 %[a], %[cs2], %[cw2], %[a]\n\t" \
  "v_accvgpr_read_b32 %[nw3], %[aw]\n\t" \
  "v_readlane_b32 %[ns3], %[hw], %[ln]\n\t" \
  "v_fma_f32 %[a], %[cs3], %[cw3], %[a]" \
  : [a]"+v"(acc), \
    [nw0]"=&v"(w0##NB), [nw1]"=&v"(w1##NB), [nw2]"=&v"(w2##NB), [nw3]"=&v"(w3##NB), \
    [ns0]"=&s"(s0##NB), [ns1]"=&s"(s1##NB), [ns2]"=&s"(s2##NB), [ns3]"=&s"(s3##NB) \
  : [cw0]"v"(w0##CB), [cw1]"v"(w1##CB), [cw2]"v"(w2##CB), [cw3]"v"(w3##CB), \
    [cs0]"s"(s0##CB), [cs1]"s"(s1##CB), [cs2]"s"(s2##CB), [cs3]"s"(s3##CB), \
    [ax]"a"(aq##np##x), [ay]"a"(aq##np##y), [az]"a"(aq##np##z), [aw]"a"(aq##np##w), \
    [hx]"v"(hq.x), [hy]"v"(hq.y), [hz]"v"(hq.z), [hw]"v"(hq.w), [ln]"i"(np));

// final quad: consume bank CB only (frozen chain tail)
#define QF(CB) asm volatile( \
  "v_fma_f32 %[a], %[cs0], %[cw0], %[a]\n\t" \
  "v_fma_f32 %[a], %[cs1], %[cw1], %[a]\n\t" \
  "v_fma_f32 %[a], %[cs2], %[cw2], %[a]\n\t" \
  "v_fma_f32 %[a], %[cs3], %[cw3], %[a]" \
  : [a]"+v"(acc) \
  : [cw0]"v"(w0##CB), [cw1]"v"(w1##CB), [cw2]"v"(w2##CB), [cw3]"v"(w3##CB), \
    [cs0]"s"(s0##CB), [cs1]"s"(s1##CB), [cs2]"s"(s2##CB), [cs3]"s"(s3##CB));

// ---- xw blocks: x[4n..4n+3] = lanes 2n,2n,2n+1,2n+1 of xv.x/.y ------------
#define XLD(B) asm volatile( \
  "v_accvgpr_read_b32 %[w0], %[ax]\n\t" \
  "v_readlane_b32 %[s0], %[vx], 0\n\t" \
  "v_accvgpr_read_b32 %[w1], %[ay]\n\t" \
  "v_readlane_b32 %[s1], %[vy], 0\n\t" \
  "v_accvgpr_read_b32 %[w2], %[az]\n\t" \
  "v_readlane_b32 %[s2], %[vx], 1\n\t" \
  "v_accvgpr_read_b32 %[w3], %[aw]\n\t" \
  "v_readlane_b32 %[s3], %[vy], 1" \
  : [w0]"=&v"(w0##B), [w1]"=&v"(w1##B), [w2]"=&v"(w2##B), [w3]"=&v"(w3##B), \
    [s0]"=&s"(s0##B), [s1]"=&s"(s1##B), [s2]"=&s"(s2##B), [s3]"=&s"(s3##B) \
  : [ax]"a"(aq0x), [ay]"a"(aq0y), [az]"a"(aq0z), [aw]"a"(aq0w), \
    [vx]"v"(xv.x), [vy]"v"(xv.y));

#define XS(n, np, CB, NB) asm volatile( \
  "v_accvgpr_read_b32 %[nw0], %[ax]\n\t" \
  "v_readlane_b32 %[ns0], %[vx], %[l0]\n\t" \
  "v_fma_f32 %[a], %[cs0], %[cw0], %[a]\n\t" \
  "v_accvgpr_read_b32 %[nw1], %[ay]\n\t" \
  "v_readlane_b32 %[ns1], %[vy], %[l0]\n\t" \
  "v_fma_f32 %[a], %[cs1], %[cw1], %[a]\n\t" \
  "v_accvgpr_read_b32 %[nw2], %[az]\n\t" \
  "v_readlane_b32 %[ns2], %[vx], %[l1]\n\t" \
  "v_fma_f32 %[a], %[cs2], %[cw2], %[a]\n\t" \
  "v_accvgpr_read_b32 %[nw3], %[aw]\n\t" \
  "v_readlane_b32 %[ns3], %[vy], %[l1]\n\t" \
  "v_fma_f32 %[a], %[cs3], %[cw3], %[a]" \
  : [a]"+v"(acc), \
    [nw0]"=&v"(w0##NB), [nw1]"=&v"(w1##NB), [nw2]"=&v"(w2##NB), [nw3]"=&v"(w3##NB), \
    [ns0]"=&s"(s0##NB), [ns1]"=&s"(s1##NB), [ns2]"=&s"(s2##NB), [ns3]"=&s"(s3##NB) \
  : [cw0]"v"(w0##CB), [cw1]"v"(w1##CB), [cw2]"v"(w2##CB), [cw3]"v"(w3##CB), \
    [cs0]"s"(s0##CB), [cs1]"s"(s1##CB), [cs2]"s"(s2##CB), [cs3]"s"(s3##CB), \
    [ax]"a"(aq##np##x), [ay]"a"(aq##np##y), [az]"a"(aq##np##z), [aw]"a"(aq##np##w), \
    [vx]"v"(xv.x), [vy]"v"(xv.y), [l0]"i"(2*(np)), [l1]"i"(2*(np)+1));

// ---------------------------------------------------------------------------
// Kernel A: xw[l][b][h] = sum_i x[b][l][i] * Wx[h][i]
// 32 AGPR quads (exactly 128 AGPRs); coalesced dwordx2/lane per row;
// interleaved triplet blocks; strict i-ascending fmaf chain (frozen).
// ---------------------------------------------------------------------------
constexpr int LC = 128;   // l-positions per block

__global__ __launch_bounds__(256, 2)
void xw_kernel(const float* __restrict__ x, const float* __restrict__ Wx,
               float* __restrict__ out) {
  const int j    = threadIdx.x;
  const int lane = j & 63;
  const int b    = blockIdx.x & (BATCH - 1);
  const int lt   = blockIdx.x >> 6;

  const f32x4* wrow = (const f32x4*)&Wx[(size_t)j * NIN];
  REP32(AQ_DECL)
  REP32(AQ_LOAD)
  BANKS

  const float* xr = x + ((size_t)b * LEN + (size_t)lt * LC) * NIN;
  float* op = out + ((size_t)lt * LC * BATCH + b) * NH + j;

  f32x2 xv = *(const f32x2*)(xr + 2 * lane);       // row 0, coalesced
  for (int ll = 0; ll < LC; ++ll) {
    const int ln = (ll + 1 < LC) ? (ll + 1) : ll;
    f32x2 xnext = *(const f32x2*)(xr + (size_t)ln * NIN + 2 * lane);
    float acc = 0.0f;
    XLD(A)
    XS(0,1,A,B)   XS(1,2,B,A)   XS(2,3,A,B)   XS(3,4,B,A)
    XS(4,5,A,B)   XS(5,6,B,A)   XS(6,7,A,B)   XS(7,8,B,A)
    XS(8,9,A,B)   XS(9,10,B,A)  XS(10,11,A,B) XS(11,12,B,A)
    XS(12,13,A,B) XS(13,14,B,A) XS(14,15,A,B) XS(15,16,B,A)
    XS(16,17,A,B) XS(17,18,B,A) XS(18,19,A,B) XS(19,20,B,A)
    XS(20,21,A,B) XS(21,22,B,A) XS(22,23,A,B) XS(23,24,B,A)
    XS(24,25,A,B) XS(25,26,B,A) XS(26,27,A,B) XS(27,28,B,A)
    XS(28,29,A,B) XS(29,30,B,A) XS(30,31,A,B)
    QF(B)
    op[(size_t)ll * BATCH * NH] = acc;
    xv = xnext;
  }
}

// ---------------------------------------------------------------------------
// Kernel B: recurrence. One batch/block, 256 threads (1 wave/SIMD). 64 AGPR
// quads = the AGPR file exactly full (nothing for the RA to park); arch
// VGPRs = working set (~35). ONE coalesced ds_read_b128/wave per step; all
// supply via interleaved triplet asm. lgkm-only barrier.
// ---------------------------------------------------------------------------
__global__ __launch_bounds__(256)
__attribute__((amdgpu_waves_per_eu(1, 1)))
void rnn_kernel(const float* __restrict__ Wh, const float* __restrict__ bh,
                const float* __restrict__ h0, float* __restrict__ io) {
  const int b    = blockIdx.x;
  const int j    = threadIdx.x;
  const int lane = j & 63;

  __shared__ __align__(16) float hbuf[2][NH];

  const f32x4* wrow = (const f32x4*)&Wh[(size_t)j * NH];
  REP64(AQ_DECL)
  REP64(AQ_LOAD)
  BANKS

  const float bias = bh[j];
  hbuf[0][j] = h0[b * NH + j];
  __syncthreads();

  float* p = io + (size_t)b * NH + j;
  const size_t stride = (size_t)BATCH * NH;

  float xw = p[0];
  int cur = 0;

  for (int l = 0; l < LEN; ++l) {
    const int ln = (l + 1 < LEN) ? (l + 1) : l;
    const float xw_next = p[(size_t)ln * stride];   // prefetch next xw

    const f32x4 hq = *(const f32x4*)&hbuf[cur][4 * lane];  // 1 coalesced read
    float acc = 0.0f;
    QLD(A)
    QS(0,1,A,B)   QS(1,2,B,A)   QS(2,3,A,B)   QS(3,4,B,A)
    QS(4,5,A,B)   QS(5,6,B,A)   QS(6,7,A,B)   QS(7,8,B,A)
    QS(8,9,A,B)   QS(9,10,B,A)  QS(10,11,A,B) QS(11,12,B,A)
    QS(12,13,A,B) QS(13,14,B,A) QS(14,15,A,B) QS(15,16,B,A)
    QS(16,17,A,B) QS(17,18,B,A) QS(18,19,A,B) QS(19,20,B,A)
    QS(20,21,A,B) QS(21,22,B,A) QS(22,23,A,B) QS(23,24,B,A)
    QS(24,25,A,B) QS(25,26,B,A) QS(26,27,A,B) QS(27,28,B,A)
    QS(28,29,A,B) QS(29,30,B,A) QS(30,31,A,B) QS(31,32,B,A)
    QS(32,33,A,B) QS(33,34,B,A) QS(34,35,A,B) QS(35,36,B,A)
    QS(36,37,A,B) QS(37,38,B,A) QS(38,39,A,B) QS(39,40,B,A)
    QS(40,41,A,B) QS(41,42,B,A) QS(42,43,A,B) QS(43,44,B,A)
    QS(44,45,A,B) QS(45,46,B,A) QS(46,47,A,B) QS(47,48,B,A)
    QS(48,49,A,B) QS(49,50,B,A) QS(50,51,A,B) QS(51,52,B,A)
    QS(52,53,A,B) QS(53,54,B,A) QS(54,55,A,B) QS(55,56,B,A)
    QS(56,57,A,B) QS(57,58,B,A) QS(58,59,A,B) QS(59,60,B,A)
    QS(60,61,A,B) QS(61,62,B,A) QS(62,63,A,B)
    QF(B)

    float pre;
    {
#pragma clang fp contract(off)
      pre = (xw + acc) + bias;                  // ((xw + hW) + b) order
    }
    const float hn = tanh_xla_fma_f32(pre);

    p[(size_t)l * stride] = hn;                 // fire-and-forget store
    hbuf[cur ^ 1][j] = hn;                      // publish state

    // lgkmcnt-only barrier: LDS visible, global store left in flight.
    asm volatile("s_waitcnt lgkmcnt(0)" ::: "memory");
    __builtin_amdgcn_s_barrier();
    asm volatile("" ::: "memory");

    cur ^= 1;
    xw = xw_next;
  }
}

extern "C" void kernel_launch(void* const* d_in, const int* in_sizes, int n_in,
                              void* d_out, int out_size, void* d_ws, size_t ws_size,
                              hipStream_t stream) {
  // Resolve inputs BY SIZE (all element counts distinct).
  const float* x  = (const float*)d_in[0];  // 16777216
  const float* h0 = (const float*)d_in[1];  // 16384
  const float* Wx = (const float*)d_in[2];  // 32768
  const float* Wh = (const float*)d_in[3];  // 65536
  const float* bh = (const float*)d_in[4];  // 256
  for (int i = 0; i < n_in; ++i) {
    switch (in_sizes[i]) {
      case 16777216: x  = (const float*)d_in[i]; break;
      case 16384:    h0 = (const float*)d_in[i]; break;
      case 32768:    Wx = (const float*)d_in[i]; break;
      case 65536:    Wh = (const float*)d_in[i]; break;
      case 256:      bh = (const float*)d_in[i]; break;
      default: break;
    }
  }
  float* out = (float*)d_out;               // [2048, 64, 256] f32

  xw_kernel<<<dim3((LEN / LC) * BATCH), dim3(256), 0, stream>>>(x, Wx, out);
  rnn_kernel<<<dim3(BATCH), dim3(256), 0, stream>>>(Wh, bh, h0, out);
}

// Round 19
// 3094.370 us; speedup vs baseline: 1.2413x; 1.2413x over previous
//
#include <hip/hip_runtime.h>

#define BATCH 64
#define LEN   2048
#define NIN   128
#define NH    256

typedef float f32x4 __attribute__((ext_vector_type(4)));
typedef float f32x2 __attribute__((ext_vector_type(2)));

// ---------------------------------------------------------------------------
// FROZEN ARITHMETIC (R7: absmax == 0.0). Do not touch:
//  - dots: single-accumulator, k-ascending fmaf chains from 0
//  - pre = (xw + acc) + bias, left-assoc, no contraction
//  - tanh = EmitFastTanh(with_fma=true): clamp ±7.99881172180175781,
//    fmaf Horner, IEEE f32 divide, |x|<0.0004 passthrough
// ---------------------------------------------------------------------------
__device__ __forceinline__ float tanh_xla_fma_f32(float x) {
  const float kClamp = 7.99881172180175781f;
  float xc = fmaxf(x, -kClamp);
  xc = fminf(xc, kClamp);
  float x2 = xc * xc;
  float num = fmaf(x2, -2.76076847742355e-16f, 2.00018790482477e-13f);
  num = fmaf(x2, num, -8.60467152213735e-11f);
  num = fmaf(x2, num, 5.12229709037114e-08f);
  num = fmaf(x2, num, 1.48572235717979e-05f);
  num = fmaf(x2, num, 6.37261928875436e-04f);
  num = fmaf(x2, num, 4.89352455891786e-03f);
  num = xc * num;
  float den = fmaf(x2, 1.19825839466702e-06f, 1.18534705686654e-04f);
  den = fmaf(x2, den, 2.26843463243900e-03f);
  den = fmaf(x2, den, 4.89352518554385e-03f);
  float r = num / den;
  return (fabsf(x) < 0.0004f) ? x : r;
}

#define PINV(v) asm("" : "+v"(v));
#define RLANE(val, q) \
  __uint_as_float(__builtin_amdgcn_readlane(__float_as_uint(val), (q)))

// R19 register doctrine (from R8-R18 evidence):
//  - gfx950 VALU cannot source AGPRs (R18 compile error) -> non-resident
//    weights cost 1 v_accvgpr_read each per step.
//  - The RA parks VGPR-resident values into FREE AGPRs with per-use copies
//    (R12/R14/R16); the only high-arch-VGPR round was R17, where the AGPR
//    file was FULL. Therefore: fill the AGPR file exactly (real + ballast),
//    keep a modest V-resident set (28 quads), compiler-scheduled body.

#define REPV28(M) M(0) M(1) M(2) M(3) M(4) M(5) M(6) M(7) \
  M(8) M(9) M(10) M(11) M(12) M(13) M(14) M(15) \
  M(16) M(17) M(18) M(19) M(20) M(21) M(22) M(23) \
  M(24) M(25) M(26) M(27)
#define REPA36(M) M(28) M(29) M(30) M(31) M(32) M(33) M(34) M(35) \
  M(36) M(37) M(38) M(39) M(40) M(41) M(42) M(43) \
  M(44) M(45) M(46) M(47) M(48) M(49) M(50) M(51) \
  M(52) M(53) M(54) M(55) M(56) M(57) M(58) M(59) \
  M(60) M(61) M(62) M(63)
#define REPX32(M) M(0) M(1) M(2) M(3) M(4) M(5) M(6) M(7) \
  M(8) M(9) M(10) M(11) M(12) M(13) M(14) M(15) \
  M(16) M(17) M(18) M(19) M(20) M(21) M(22) M(23) \
  M(24) M(25) M(26) M(27) M(28) M(29) M(30) M(31)
#define REPB64(M) REPX32(M) M(32) M(33) M(34) M(35) M(36) M(37) M(38) M(39) \
  M(40) M(41) M(42) M(43) M(44) M(45) M(46) M(47) \
  M(48) M(49) M(50) M(51) M(52) M(53) M(54) M(55) \
  M(56) M(57) M(58) M(59) M(60) M(61) M(62) M(63)

// V-resident weight quads
#define WQ_DECL(n) f32x4 wq##n;
#define WQ_LOAD(n) wq##n = wrow[n]; PINV(wq##n)
// AGPR-resident weight quads (results used in loop -> not DCE'd)
#define AQ_DECL(n) float aq##n##x, aq##n##y, aq##n##z, aq##n##w;
#define AQ_WRITE(n) { f32x4 v = wrow[n]; \
  asm("v_accvgpr_write_b32 %0, %1" : "=a"(aq##n##x) : "v"(v.x)); \
  asm("v_accvgpr_write_b32 %0, %1" : "=a"(aq##n##y) : "v"(v.y)); \
  asm("v_accvgpr_write_b32 %0, %1" : "=a"(aq##n##z) : "v"(v.z)); \
  asm("v_accvgpr_write_b32 %0, %1" : "=a"(aq##n##w) : "v"(v.w)); }
// Ballast AGPR quads (fill the file so the RA has NO parking lot);
// kept live by zero-instruction volatile asm inside the loop.
#define BQ_DECL(n) float bq##n##x, bq##n##y, bq##n##z, bq##n##w;
#define BQ_WRITE(n) { f32x4 v = wrow[(n) & 31]; \
  asm("v_accvgpr_write_b32 %0, %1" : "=a"(bq##n##x) : "v"(v.x)); \
  asm("v_accvgpr_write_b32 %0, %1" : "=a"(bq##n##y) : "v"(v.y)); \
  asm("v_accvgpr_write_b32 %0, %1" : "=a"(bq##n##z) : "v"(v.z)); \
  asm("v_accvgpr_write_b32 %0, %1" : "=a"(bq##n##w) : "v"(v.w)); }
#define BQ_KEEP(n) asm volatile("" :: "a"(bq##n##x), "a"(bq##n##y), \
                                      "a"(bq##n##z), "a"(bq##n##w));

// FROZEN k-ascending chain, V-quad (h[4n+c] = lane n, comp c of hq)
#define STEPV(n) \
  acc = fmaf(RLANE(hq.x, n), wq##n.x, acc); \
  acc = fmaf(RLANE(hq.y, n), wq##n.y, acc); \
  acc = fmaf(RLANE(hq.z, n), wq##n.z, acc); \
  acc = fmaf(RLANE(hq.w, n), wq##n.w, acc);
// A-quad: reads carry a loop-varying dummy dep (hq.x) -> no LICM hoist,
// but the scheduler may interleave them freely (non-volatile).
#define STEPA(n) { float t0, t1, t2, t3; \
  asm("v_accvgpr_read_b32 %0, %1" : "=v"(t0) : "a"(aq##n##x), "v"(hq.x)); \
  asm("v_accvgpr_read_b32 %0, %1" : "=v"(t1) : "a"(aq##n##y), "v"(hq.x)); \
  asm("v_accvgpr_read_b32 %0, %1" : "=v"(t2) : "a"(aq##n##z), "v"(hq.x)); \
  asm("v_accvgpr_read_b32 %0, %1" : "=v"(t3) : "a"(aq##n##w), "v"(hq.x)); \
  acc = fmaf(RLANE(hq.x, n), t0, acc); \
  acc = fmaf(RLANE(hq.y, n), t1, acc); \
  acc = fmaf(RLANE(hq.z, n), t2, acc); \
  acc = fmaf(RLANE(hq.w, n), t3, acc); }

// xw chain quad: x[4n..4n+3] = lanes 2n,2n,2n+1,2n+1 of xv.x/.y.
#define XSTEP(n) \
  acc = fmaf(RLANE(xv.x, 2*(n)    ), wq##n.x, acc); \
  acc = fmaf(RLANE(xv.y, 2*(n)    ), wq##n.y, acc); \
  acc = fmaf(RLANE(xv.x, 2*(n) + 1), wq##n.z, acc); \
  acc = fmaf(RLANE(xv.y, 2*(n) + 1), wq##n.w, acc);

// ---------------------------------------------------------------------------
// Kernel A: xw[l][b][h] = sum_i x[b][l][i] * Wx[h][i]
// 1 wave/SIMD; 32 V-quads (128 regs) + AGPR file filled with 256 ballast
// regs -> no parking. Coalesced dwordx2/lane per row, 2-row prefetch.
// ---------------------------------------------------------------------------
constexpr int LC = 128;   // l-positions per block

__global__ __launch_bounds__(256)
__attribute__((amdgpu_waves_per_eu(1, 1)))
void xw_kernel(const float* __restrict__ x, const float* __restrict__ Wx,
               float* __restrict__ out) {
  const int j    = threadIdx.x;
  const int lane = j & 63;
  const int b    = blockIdx.x & (BATCH - 1);
  const int lt   = blockIdx.x >> 6;

  const f32x4* wrow = (const f32x4*)&Wx[(size_t)j * NIN];
  REPX32(WQ_DECL)
  REPB64(BQ_DECL)
  REPX32(WQ_LOAD)
  REPB64(BQ_WRITE)

  const float* xr = x + ((size_t)b * LEN + (size_t)lt * LC) * NIN;
  float* op = out + ((size_t)lt * LC * BATCH + b) * NH + j;

  f32x2 xv  = *(const f32x2*)(xr + 2 * lane);               // row 0
  f32x2 xp1 = *(const f32x2*)(xr + (size_t)NIN + 2 * lane); // row 1
  for (int ll = 0; ll < LC; ++ll) {
    const int ln = (ll + 2 < LC) ? (ll + 2) : (LC - 1);
    f32x2 xp2 = *(const f32x2*)(xr + (size_t)ln * NIN + 2 * lane);
    float acc = 0.0f;
    REPX32(XSTEP)
    op[(size_t)ll * BATCH * NH] = acc;
    REPB64(BQ_KEEP)
    xv = xp1;
    xp1 = xp2;
  }
}

// ---------------------------------------------------------------------------
// Kernel B: recurrence. One batch/block, 256 threads (1 wave/SIMD).
// Weights: quads 0..27 in arch VGPRs (112 regs, real residency — AGPR file
// is full so no parking lot), quads 28..63 in AGPRs (144 regs) read per
// step, + 112 ballast AGPRs = file exactly 256/256. ONE coalesced
// ds_read_b128/wave per step; readlane broadcast; lgkm-only barrier.
// ---------------------------------------------------------------------------
__global__ __launch_bounds__(256)
__attribute__((amdgpu_waves_per_eu(1, 1)))
void rnn_kernel(const float* __restrict__ Wh, const float* __restrict__ bh,
                const float* __restrict__ h0, float* __restrict__ io) {
  const int b    = blockIdx.x;
  const int j    = threadIdx.x;
  const int lane = j & 63;

  __shared__ __align__(16) float hbuf[2][NH];

  const f32x4* wrow = (const f32x4*)&Wh[(size_t)j * NH];
  REPV28(WQ_DECL)
  REPA36(AQ_DECL)
  REPV28(BQ_DECL)
  REPV28(WQ_LOAD)
  REPA36(AQ_WRITE)
  REPV28(BQ_WRITE)

  const float bias = bh[j];
  hbuf[0][j] = h0[b * NH + j];
  __syncthreads();

  float* p = io + (size_t)b * NH + j;
  const size_t stride = (size_t)BATCH * NH;

  float xw = p[0];
  int cur = 0;

  for (int l = 0; l < LEN; ++l) {
    const int ln = (l + 1 < LEN) ? (l + 1) : l;
    const float xw_next = p[(size_t)ln * stride];   // prefetch next xw

    const f32x4 hq = *(const f32x4*)&hbuf[cur][4 * lane];  // 1 coalesced read
    float acc = 0.0f;
    REPV28(STEPV)        // k = 0..111  (V-resident)
    REPA36(STEPA)        // k = 112..255 (AGPR, read per step)

    float pre;
    {
#pragma clang fp contract(off)
      pre = (xw + acc) + bias;                  // ((xw + hW) + b) order
    }
    const float hn = tanh_xla_fma_f32(pre);

    p[(size_t)l * stride] = hn;                 // fire-and-forget store
    hbuf[cur ^ 1][j] = hn;                      // publish state
    REPV28(BQ_KEEP)                             // ballast live (0 instrs)

    // lgkmcnt-only barrier: LDS visible, global store left in flight.
    asm volatile("s_waitcnt lgkmcnt(0)" ::: "memory");
    __builtin_amdgcn_s_barrier();
    asm volatile("" ::: "memory");

    cur ^= 1;
    xw = xw_next;
  }
}

extern "C" void kernel_launch(void* const* d_in, const int* in_sizes, int n_in,
                              void* d_out, int out_size, void* d_ws, size_t ws_size,
                              hipStream_t stream) {
  // Resolve inputs BY SIZE (all element counts distinct).
  const float* x  = (const float*)d_in[0];  // 16777216
  const float* h0 = (const float*)d_in[1];  // 16384
  const float* Wx = (const float*)d_in[2];  // 32768
  const float* Wh = (const float*)d_in[3];  // 65536
  const float* bh = (const float*)d_in[4];  // 256
  for (int i = 0; i < n_in; ++i) {
    switch (in_sizes[i]) {
      case 16777216: x  = (const float*)d_in[i]; break;
      case 16384:    h0 = (const float*)d_in[i]; break;
      case 32768:    Wx = (const float*)d_in[i]; break;
      case 65536:    Wh = (const float*)d_in[i]; break;
      case 256:      bh = (const float*)d_in[i]; break;
      default: break;
    }
  }
  float* out = (float*)d_out;               // [2048, 64, 256] f32

  xw_kernel<<<dim3((LEN / LC) * BATCH), dim3(256), 0, stream>>>(x, Wx, out);
  rnn_kernel<<<dim3(BATCH), dim3(256), 0, stream>>>(Wh, bh, h0, out);
}